// Round 2
// baseline (357.102 us; speedup 1.0000x reference)
//
#include <hip/hip_runtime.h>

// QuantumLayer: h = x @ W + b  (B x 1024 @ 1024 x 2), row-normalize h,
// then a fixed 2-qubit circuit -> [B,2] <Z> values.
// HBM-bound on reading x (268 MB). One wave per row-group, butterfly reduce.
// R1: all-scalar circuit (no local arrays, no pointer-out sincos) to kill
// scratch traffic; 4 rows per step for 16 loads in flight.

#define WAVES_PER_BLOCK 4
#define ROWS_PER_WAVE   8
#define ROWS_PER_BLOCK  (WAVES_PER_BLOCK * ROWS_PER_WAVE)

__device__ __forceinline__ float2 run_circuit(
    float h0, float h1,
    float c00, float s00, float c01, float s01,   // layer 0: wire0, wire1
    float c10, float s10, float c11, float s11)   // layer 1: wire0, wire1
{
    float inv = rsqrtf(fmaxf(h0 * h0 + h1 * h1, 1e-12f));
    float t0 = 0.5f * h0 * inv;
    float t1 = 0.5f * h1 * inv;
    float s0 = __sinf(t0), c0 = __cosf(t0);
    float s1 = __sinf(t1), c1 = __cosf(t1);

    // state after RX(h0) on wire0, RX(h1) on wire1 applied to |00>:
    float r00 = c0 * c1,   i00 = 0.0f;
    float r01 = 0.0f,      i01 = -c0 * s1;
    float r10 = 0.0f,      i10 = -s0 * c1;
    float r11 = -s0 * s1,  i11 = 0.0f;

    float ar, ai, br, bi, tr, ti;

#define RX_W0(c, s)                                                  \
    ar = r00; ai = i00; br = r10; bi = i10;                          \
    r00 = c * ar + s * bi; i00 = c * ai - s * br;                    \
    r10 = s * ai + c * br; i10 = c * bi - s * ar;                    \
    ar = r01; ai = i01; br = r11; bi = i11;                          \
    r01 = c * ar + s * bi; i01 = c * ai - s * br;                    \
    r11 = s * ai + c * br; i11 = c * bi - s * ar;

#define RX_W1(c, s)                                                  \
    ar = r00; ai = i00; br = r01; bi = i01;                          \
    r00 = c * ar + s * bi; i00 = c * ai - s * br;                    \
    r01 = s * ai + c * br; i01 = c * bi - s * ar;                    \
    ar = r10; ai = i10; br = r11; bi = i11;                          \
    r10 = c * ar + s * bi; i10 = c * ai - s * br;                    \
    r11 = s * ai + c * br; i11 = c * bi - s * ar;

#define CNOT01()                                                     \
    tr = r10; ti = i10; r10 = r11; i10 = i11; r11 = tr; i11 = ti;

    RX_W0(c00, s00)
    RX_W1(c01, s01)
    CNOT01()
    RX_W0(c10, s10)
    RX_W1(c11, s11)
    CNOT01()

#undef RX_W0
#undef RX_W1
#undef CNOT01

    float p00 = r00 * r00 + i00 * i00;
    float p01 = r01 * r01 + i01 * i01;
    float p10 = r10 * r10 + i10 * i10;
    float p11 = r11 * r11 + i11 * i11;

    float2 z;
    z.x = (p00 + p01) - (p10 + p11);
    z.y = (p00 + p10) - (p01 + p11);
    return z;
}

__global__ __launch_bounds__(256) void qlayer_kernel(
    const float* __restrict__ x,    // [B,1024]
    const float* __restrict__ w,    // [1024,2] row-major: w[d*2+q]
    const float* __restrict__ bias, // [2]
    const float* __restrict__ wq,   // [2,2]
    float* __restrict__ out,        // [B,2]
    int B)
{
    const int lane = threadIdx.x & 63;
    const int wave = threadIdx.x >> 6;
    const int rowBase = (blockIdx.x * WAVES_PER_BLOCK + wave) * ROWS_PER_WAVE;
    if (rowBase >= B) return;

    // Lane handles float4-indices f = lane + 64*j (j=0..3) of the 256-float4
    // row; weight fragment for d=4f is two float4 at indices 2f, 2f+1.
    const float4* __restrict__ w4 = (const float4*)w;
    float4 wA0, wB0, wA1, wB1, wA2, wB2, wA3, wB3;
    wA0 = w4[2 * (lane +   0)]; wB0 = w4[2 * (lane +   0) + 1];
    wA1 = w4[2 * (lane +  64)]; wB1 = w4[2 * (lane +  64) + 1];
    wA2 = w4[2 * (lane + 128)]; wB2 = w4[2 * (lane + 128) + 1];
    wA3 = w4[2 * (lane + 192)]; wB3 = w4[2 * (lane + 192) + 1];

    const float b0 = bias[0], b1 = bias[1];

    // Per-layer RX half-angle sin/cos (scalars, no arrays)
    const float c00 = __cosf(0.5f * wq[0]), s00 = __sinf(0.5f * wq[0]);
    const float c01 = __cosf(0.5f * wq[1]), s01 = __sinf(0.5f * wq[1]);
    const float c10 = __cosf(0.5f * wq[2]), s10 = __sinf(0.5f * wq[2]);
    const float c11 = __cosf(0.5f * wq[3]), s11 = __sinf(0.5f * wq[3]);

    float2* __restrict__ out2 = (float2*)out;

#pragma unroll
    for (int r = 0; r < ROWS_PER_WAVE; r += 4) {
        const int row0 = rowBase + r;

        const float4* __restrict__ xA = (const float4*)x + (size_t)(row0 + 0) * 256;
        const float4* __restrict__ xB = (const float4*)x + (size_t)(row0 + 1) * 256;
        const float4* __restrict__ xC = (const float4*)x + (size_t)(row0 + 2) * 256;
        const float4* __restrict__ xD = (const float4*)x + (size_t)(row0 + 3) * 256;

        float a0 = 0.f, a1 = 0.f, b0s = 0.f, b1s = 0.f;
        float e0 = 0.f, e1 = 0.f, d0 = 0.f, d1 = 0.f;

#define DOT(v, wA, wB, acc0, acc1)                                   \
        acc0 = fmaf(v.x, wA.x, acc0); acc1 = fmaf(v.x, wA.y, acc1);  \
        acc0 = fmaf(v.y, wA.z, acc0); acc1 = fmaf(v.y, wA.w, acc1);  \
        acc0 = fmaf(v.z, wB.x, acc0); acc1 = fmaf(v.z, wB.y, acc1);  \
        acc0 = fmaf(v.w, wB.z, acc0); acc1 = fmaf(v.w, wB.w, acc1);

#define STEP(j, wA, wB)                                              \
        {                                                            \
            float4 va = xA[lane + 64 * j];                           \
            float4 vb = xB[lane + 64 * j];                           \
            float4 vc = xC[lane + 64 * j];                           \
            float4 vd = xD[lane + 64 * j];                           \
            DOT(va, wA, wB, a0, a1)                                  \
            DOT(vb, wA, wB, b0s, b1s)                                \
            DOT(vc, wA, wB, e0, e1)                                  \
            DOT(vd, wA, wB, d0, d1)                                  \
        }

        STEP(0, wA0, wB0)
        STEP(1, wA1, wB1)
        STEP(2, wA2, wB2)
        STEP(3, wA3, wB3)

#undef STEP
#undef DOT

        // butterfly reduce across the 64-lane wave (8 independent chains)
#pragma unroll
        for (int off = 32; off >= 1; off >>= 1) {
            a0  += __shfl_xor(a0, off, 64);
            a1  += __shfl_xor(a1, off, 64);
            b0s += __shfl_xor(b0s, off, 64);
            b1s += __shfl_xor(b1s, off, 64);
            e0  += __shfl_xor(e0, off, 64);
            e1  += __shfl_xor(e1, off, 64);
            d0  += __shfl_xor(d0, off, 64);
            d1  += __shfl_xor(d1, off, 64);
        }

        float2 zA = run_circuit(a0 + b0, a1 + b1, c00, s00, c01, s01, c10, s10, c11, s11);
        float2 zB = run_circuit(b0s + b0, b1s + b1, c00, s00, c01, s01, c10, s10, c11, s11);
        float2 zC = run_circuit(e0 + b0, e1 + b1, c00, s00, c01, s01, c10, s10, c11, s11);
        float2 zD = run_circuit(d0 + b0, d1 + b1, c00, s00, c01, s01, c10, s10, c11, s11);

        if (lane == 0) {
            out2[row0 + 0] = zA;
            out2[row0 + 1] = zB;
            out2[row0 + 2] = zC;
            out2[row0 + 3] = zD;
        }
    }
}

extern "C" void kernel_launch(void* const* d_in, const int* in_sizes, int n_in,
                              void* d_out, int out_size, void* d_ws, size_t ws_size,
                              hipStream_t stream) {
    const float* x    = (const float*)d_in[0];
    const float* w    = (const float*)d_in[1];
    const float* bias = (const float*)d_in[2];
    const float* wq   = (const float*)d_in[3];
    float* out = (float*)d_out;

    const int B = in_sizes[0] / 1024;
    const int grid = (B + ROWS_PER_BLOCK - 1) / ROWS_PER_BLOCK;
    qlayer_kernel<<<grid, 256, 0, stream>>>(x, w, bias, wq, out, B);
}